// Round 2
// baseline (274.363 us; speedup 1.0000x reference)
//
#include <hip/hip_runtime.h>
#include <cstdint>
#include <cstddef>

// Low-rank bilinear attention, MI355X/gfx950.
// out = softmax((x@W1)(W2@x^T)/sqrt(512)) @ x,  x:[16,2048,512] fp32.
// Pipeline: K0 transpose x->xT f16 | K1 left/rightT factors via MFMA |
//           K2 softmax denominators | K3 fused P-recompute + P@x MFMA GEMM.

typedef float    f32x4 __attribute__((ext_vector_type(4)));
typedef _Float16 half8 __attribute__((ext_vector_type(8)));
typedef _Float16 half4 __attribute__((ext_vector_type(4)));
typedef _Float16 half2 __attribute__((ext_vector_type(2)));

#define B_  16
#define A_  2048
#define D_  512
#define SCALE 0.04419417382415922f  // 1/sqrt(512)

// ---------------- K0: x [b][c][d] fp32 -> xT [b][d][c] f16 ----------------
__global__ __launch_bounds__(256) void k0_transpose(const float* __restrict__ x,
                                                    _Float16* __restrict__ xT) {
    __shared__ float xs[64][65];
    int t = threadIdx.x;
    int bid = blockIdx.x;
    int b = bid >> 8, rem = bid & 255;
    int c0 = (rem >> 3) << 6, d0 = (rem & 7) << 6;
    const float* xb = x + ((size_t)b * A_ + c0) * D_ + d0;
#pragma unroll
    for (int j = 0; j < 4; ++j) {
        int idx = t + 256 * j;
        int c = idx >> 4, dq = (idx & 15) << 2;
        float4 v = *(const float4*)(xb + (size_t)c * D_ + dq);
        xs[c][dq] = v.x; xs[c][dq + 1] = v.y; xs[c][dq + 2] = v.z; xs[c][dq + 3] = v.w;
    }
    __syncthreads();
    _Float16* xo = xT + ((size_t)b * D_ + d0) * A_ + c0;
#pragma unroll
    for (int j = 0; j < 4; ++j) {
        int idx = t + 256 * j;
        int d = idx >> 4, cq = (idx & 15) << 2;
        half4 h;
        h[0] = (_Float16)xs[cq][d];     h[1] = (_Float16)xs[cq + 1][d];
        h[2] = (_Float16)xs[cq + 2][d]; h[3] = (_Float16)xs[cq + 3][d];
        *(half4*)(xo + (size_t)d * A_ + cq) = h;
    }
}

// -------- K1: left[row][10] fp32 (pre-scaled), rightT[row][12] f16 --------
// One MFMA pass over x. Wc LDS: rows 0..9 = W1 cols * SCALE, rows 16..25 = W2
// rows; pad rows zeroed so unused MFMA columns are exactly 0.
__global__ __launch_bounds__(256) void k1_factors(const float* __restrict__ x,
                                                  const float* __restrict__ W1,
                                                  const float* __restrict__ W2,
                                                  float* __restrict__ left,
                                                  _Float16* __restrict__ rightT) {
    __shared__ _Float16 Wc[32 * 520];
    int t = threadIdx.x;
    for (int i = t; i < 2560; i += 256) {          // W1 (scaled), transposed
        int r = i >> 8, d = (i & 255) << 1;
        half2 h;
        h[0] = (_Float16)(W1[d * 10 + r] * SCALE);
        h[1] = (_Float16)(W1[(d + 1) * 10 + r] * SCALE);
        *(half2*)&Wc[r * 520 + d] = h;
    }
    for (int i = t; i < 2560; i += 256) {          // W2 rows
        int r = i >> 8, d = (i & 255) << 1;
        half2 h;
        h[0] = (_Float16)W2[r * 512 + d];
        h[1] = (_Float16)W2[r * 512 + d + 1];
        *(half2*)&Wc[(16 + r) * 520 + d] = h;
    }
    for (int i = t; i < 3120; i += 256) {          // zero pad rows 10-15, 26-31
        int rz = i / 260, dw = i % 260;
        int row = rz < 6 ? 10 + rz : 20 + rz;
        *(uint32_t*)&Wc[row * 520 + dw * 2] = 0u;
    }
    __syncthreads();

    int lane = t & 63, w = t >> 6;
    int quad = lane >> 4, col = lane & 15;
    int r0 = (blockIdx.x * 4 + w) * 16;
    int mrow = r0 + col;
    const float* xr = x + (size_t)mrow * 512;
    f32x4 accA = {0.f, 0.f, 0.f, 0.f}, accB = {0.f, 0.f, 0.f, 0.f};
#pragma unroll
    for (int kt = 0; kt < 16; ++kt) {
        int k = kt * 32 + quad * 8;
        float4 v0 = *(const float4*)(xr + k);
        float4 v1 = *(const float4*)(xr + k + 4);
        half8 af;
        af[0] = (_Float16)v0.x; af[1] = (_Float16)v0.y; af[2] = (_Float16)v0.z; af[3] = (_Float16)v0.w;
        af[4] = (_Float16)v1.x; af[5] = (_Float16)v1.y; af[6] = (_Float16)v1.z; af[7] = (_Float16)v1.w;
        half8 bf0 = *(const half8*)&Wc[col * 520 + k];
        half8 bf1 = *(const half8*)&Wc[(col + 16) * 520 + k];
        accA = __builtin_amdgcn_mfma_f32_16x16x32_f16(af, bf0, accA, 0, 0, 0);
        accB = __builtin_amdgcn_mfma_f32_16x16x32_f16(af, bf1, accB, 0, 0, 0);
    }
#pragma unroll
    for (int q = 0; q < 4; ++q) {
        int row = r0 + quad * 4 + q;
        if (col < 10) left[(size_t)row * 10 + col] = accA[q];
        if (col < 12) rightT[(size_t)row * 12 + col] = (_Float16)accB[q];  // cols 10,11 are exact 0
    }
}

// ------------- K2: linv[row] = 1 / sum_c exp(left[row].rightT[c]) -------------
__global__ __launch_bounds__(256) void k2_denom(const float* __restrict__ left,
                                                const _Float16* __restrict__ rightT,
                                                float* __restrict__ linv) {
    int t = threadIdx.x;
    int lane = t & 63, g = t >> 6;
    int base = blockIdx.x * 16 + g * 4;          // 4 rows per wave
    int b = base >> 11;
    const _Float16* rT = rightT + (size_t)(b << 11) * 12;
    float lf[4][10];
#pragma unroll
    for (int j = 0; j < 4; ++j)
#pragma unroll
        for (int r = 0; r < 10; ++r) lf[j][r] = left[(size_t)(base + j) * 10 + r];
    float lsum[4] = {0.f, 0.f, 0.f, 0.f};
    for (int i = 0; i < 32; ++i) {
        int c = lane + (i << 6);
        const half4* rp = (const half4*)(rT + (size_t)c * 12);
        half4 h0 = rp[0], h1 = rp[1], h2 = rp[2];
        float rv[10] = {(float)h0[0], (float)h0[1], (float)h0[2], (float)h0[3],
                        (float)h1[0], (float)h1[1], (float)h1[2], (float)h1[3],
                        (float)h2[0], (float)h2[1]};
#pragma unroll
        for (int j = 0; j < 4; ++j) {
            float s = 0.f;
#pragma unroll
            for (int r = 0; r < 10; ++r) s += lf[j][r] * rv[r];
            lsum[j] += __expf(s);
        }
    }
#pragma unroll
    for (int j = 0; j < 4; ++j) {
        lsum[j] += __shfl_xor(lsum[j], 1);
        lsum[j] += __shfl_xor(lsum[j], 2);
        lsum[j] += __shfl_xor(lsum[j], 4);
        lsum[j] += __shfl_xor(lsum[j], 8);
        lsum[j] += __shfl_xor(lsum[j], 16);
        lsum[j] += __shfl_xor(lsum[j], 32);
    }
    if (lane == 0) {
#pragma unroll
        for (int j = 0; j < 4; ++j) linv[base + j] = 1.0f / lsum[j];
    }
}

// ------------- K3: fused P recompute (MFMA) + (P@x) MFMA GEMM -------------
// Block: 128a x 128d tile, 4 waves (64x64 each), K-loop c in steps of 32.
// P tile computed via padded-K 16x16x32 MFMAs from left-regs x rlds, exp'd,
// round-tripped through Ps LDS into A-fragment layout. XT staged by
// global_load_lds (16B) with XOR chunk swizzle to tame bank conflicts.
__global__ __launch_bounds__(256, 3) void k3_attn(const _Float16* __restrict__ xT,
                                                  const float* __restrict__ left,
                                                  const _Float16* __restrict__ rightT,
                                                  const float* __restrict__ linv,
                                                  float* __restrict__ out) {
    __shared__ _Float16 XTl[128 * 32];   // [d-local][c-chunk], rows 64B, swizzled
    __shared__ _Float16 Ps[128 * 40];    // [a-local][c], stride 40 f16 (2-way banks)
    __shared__ _Float16 rl[32 * 40];     // [c-local][r padded]
    int t = threadIdx.x, lane = t & 63, w = t >> 6;
    int quad = lane >> 4, c16 = lane & 15;
    int bid = blockIdx.x;
    int nb = bid & 3, at = (bid >> 2) & 15, b = bid >> 6;
    int a0 = at << 7, n0 = nb << 7;
    int waveM = w & 1, waveN = w >> 1;

    // zero rl pad r in [12,32) for ALL 32 rows (320 dwords, strided over 256 thr)
    for (int i = t; i < 320; i += 256) {
        int c = i / 10, dw = i % 10;
        *(uint32_t*)((char*)rl + c * 80 + 24 + dw * 4) = 0u;
    }

    // left A-frags (static per block): wave w owns P row-tiles m = 2w, 2w+1
    half8 lf[2];
#pragma unroll
    for (int i = 0; i < 2; ++i) {
        int arow = a0 + (2 * w + i) * 16 + c16;
        const float* lp = left + (size_t)((b << 11) + arow) * 10;
#pragma unroll
        for (int j = 0; j < 8; ++j) {
            int r = quad * 8 + j;
            lf[i][j] = (r < 10) ? (_Float16)lp[r] : (_Float16)0.f;
        }
    }

    f32x4 acc[4][4];
#pragma unroll
    for (int mi = 0; mi < 4; ++mi)
#pragma unroll
        for (int ni = 0; ni < 4; ++ni) acc[mi][ni] = (f32x4){0.f, 0.f, 0.f, 0.f};

    const _Float16* xTb = xT + ((size_t)b * D_ + n0) * A_;
    const _Float16* rTb = rightT + (size_t)(b << 11) * 12;

    int psA[4];
#pragma unroll
    for (int mi = 0; mi < 4; ++mi) psA[mi] = (waveM * 64 + mi * 16 + c16) * 80 + quad * 16;
    int xtB[4];
#pragma unroll
    for (int ni = 0; ni < 4; ++ni) {
        int nr = waveN * 64 + ni * 16 + c16;
        xtB[ni] = nr * 64 + ((quad ^ ((nr >> 1) & 3)) << 4);
    }
    int rlB[2];
#pragma unroll
    for (int kh = 0; kh < 2; ++kh) rlB[kh] = (kh * 16 + c16) * 80 + quad * 16;

    int nloc0 = w * 32 + (lane >> 2);
    int kq = lane & 3;

    for (int kt = 0; kt < 64; ++kt) {
        int c0 = kt << 5;
        __syncthreads();
        if (t < 192) {                    // stage rightT tile: 32c x 6 dwords
            int c = t / 6, dw = t % 6;
            uint32_t v = *(const uint32_t*)((const char*)(rTb + (size_t)(c0 + c) * 12) + dw * 4);
            *(uint32_t*)((char*)rl + c * 80 + dw * 4) = v;
        }
#pragma unroll
        for (int cc = 0; cc < 2; ++cc) {  // DMA XT tile: 16 rows x 64B per call
            int nl = nloc0 + cc * 16;
            int kqs = kq ^ ((nl >> 1) & 3);
            const _Float16* src = xTb + (size_t)nl * A_ + c0 + kqs * 8;
            _Float16* dst = &XTl[(w * 32 + cc * 16) * 32];
            __builtin_amdgcn_global_load_lds((const __attribute__((address_space(1))) void*)src,
                                             (__attribute__((address_space(3))) void*)dst,
                                             16, 0, 0);
        }
        __syncthreads();
        // P phase: scores -> exp -> Ps (A-operand layout)
#pragma unroll
        for (int kh = 0; kh < 2; ++kh) {
            half8 bfr = *(const half8*)((const char*)rl + rlB[kh]);
#pragma unroll
            for (int i = 0; i < 2; ++i) {
                f32x4 z = {0.f, 0.f, 0.f, 0.f};
                f32x4 pc = __builtin_amdgcn_mfma_f32_16x16x32_f16(lf[i], bfr, z, 0, 0, 0);
#pragma unroll
                for (int q = 0; q < 4; ++q) {
                    float p = __expf(pc[q]);
                    Ps[((2 * w + i) * 16 + quad * 4 + q) * 40 + kh * 16 + c16] = (_Float16)p;
                }
            }
        }
        __syncthreads();
        // main GEMM phase
        half8 af[4], bf[4];
#pragma unroll
        for (int mi = 0; mi < 4; ++mi) af[mi] = *(const half8*)((const char*)Ps + psA[mi]);
#pragma unroll
        for (int ni = 0; ni < 4; ++ni) bf[ni] = *(const half8*)((const char*)XTl + xtB[ni]);
#pragma unroll
        for (int mi = 0; mi < 4; ++mi)
#pragma unroll
            for (int ni = 0; ni < 4; ++ni)
                acc[mi][ni] = __builtin_amdgcn_mfma_f32_16x16x32_f16(af[mi], bf[ni], acc[mi][ni], 0, 0, 0);
    }

    float* ob = out + ((size_t)b * A_ + a0) * D_ + n0;
#pragma unroll
    for (int mi = 0; mi < 4; ++mi) {
#pragma unroll
        for (int q = 0; q < 4; ++q) {
            int ar = waveM * 64 + mi * 16 + quad * 4 + q;
            float sc = linv[(b << 11) + a0 + ar];
#pragma unroll
            for (int ni = 0; ni < 4; ++ni)
                ob[(size_t)ar * D_ + waveN * 64 + ni * 16 + c16] = acc[mi][ni][q] * sc;
        }
    }
}

extern "C" void kernel_launch(void* const* d_in, const int* in_sizes, int n_in,
                              void* d_out, int out_size, void* d_ws, size_t ws_size,
                              hipStream_t stream) {
    const float* x  = (const float*)d_in[0];
    const float* W1 = (const float*)d_in[1];
    const float* W2 = (const float*)d_in[2];
    float* out = (float*)d_out;
    char* ws = (char*)d_ws;
    // ws layout (bytes): xT f16 [16][512][2048] @0 (33,554,432)
    //                    left fp32 [32768][10] @33,554,432 (1,310,720)
    //                    rightT f16 [32768][12] @34,865,152 (786,432)
    //                    linv fp32 [32768] @35,651,584 (131,072)   total ~35.8 MB
    _Float16* xT    = (_Float16*)ws;
    float*    left  = (float*)(ws + 33554432);
    _Float16* rightT= (_Float16*)(ws + 34865152);
    float*    linv  = (float*)(ws + 35651584);

    k0_transpose<<<4096, 256, 0, stream>>>(x, xT);
    k1_factors<<<512, 256, 0, stream>>>(x, W1, W2, left, rightT);
    k2_denom<<<2048, 256, 0, stream>>>(left, rightT, linv);
    k3_attn<<<1024, 256, 0, stream>>>(xT, left, rightT, linv, out);
}

// Round 3
// 233.709 us; speedup vs baseline: 1.1740x; 1.1740x over previous
//
#include <hip/hip_runtime.h>
#include <cstdint>
#include <cstddef>

// Low-rank bilinear attention, MI355X/gfx950.
// out = softmax((x@W1)(W2@x^T)/sqrt(512)) @ x,  x:[16,2048,512] fp32.
// K01: read x once -> xT f16 [b][d][c] + left fp32 + rightT f16 (factor MFMAs).
// K3:  fused P-recompute (MFMA) + row-sum softmax + (P@x) MFMA GEMM, 128x256 tile.

typedef float    f32x4 __attribute__((ext_vector_type(4)));
typedef _Float16 half8 __attribute__((ext_vector_type(8)));
typedef _Float16 half4 __attribute__((ext_vector_type(4)));
typedef _Float16 half2 __attribute__((ext_vector_type(2)));

#define B_  16
#define A_  2048
#define D_  512
#define SCALE 0.04419417382415922f  // 1/sqrt(512)

// ---------------- K01: transpose + factors, x read once ----------------
// Block = 64 a-rows x full D. 8 chunks of 64 d through swizzled fp32 LDS tile.
// xs element (c, d=ch*4+e) stored at xs[c*64 + (ch^(c&15))*4 + e]  -> 2-way max
// in all phases, 16B-aligned vector loads for MFMA A-fragments.
__global__ __launch_bounds__(256) void k01_prep(const float* __restrict__ x,
                                                const float* __restrict__ W1,
                                                const float* __restrict__ W2,
                                                _Float16* __restrict__ xT,
                                                float* __restrict__ left,
                                                _Float16* __restrict__ rightT) {
    __shared__ float xs[64 * 64];
    __shared__ _Float16 Wc[32 * 520];
    int t = threadIdx.x;
    for (int i = t; i < 2560; i += 256) {          // W1 (scaled), transposed
        int r = i >> 8, d = (i & 255) << 1;
        half2 h;
        h[0] = (_Float16)(W1[d * 10 + r] * SCALE);
        h[1] = (_Float16)(W1[(d + 1) * 10 + r] * SCALE);
        *(half2*)&Wc[r * 520 + d] = h;
    }
    for (int i = t; i < 2560; i += 256) {          // W2 rows
        int r = i >> 8, d = (i & 255) << 1;
        half2 h;
        h[0] = (_Float16)W2[r * 512 + d];
        h[1] = (_Float16)W2[r * 512 + d + 1];
        *(half2*)&Wc[(16 + r) * 520 + d] = h;
    }
    for (int i = t; i < 3120; i += 256) {          // zero pad rows 10-15, 26-31
        int rz = i / 260, dw = i % 260;
        int row = rz < 6 ? 10 + rz : 20 + rz;
        *(uint32_t*)&Wc[row * 520 + dw * 2] = 0u;
    }

    int bid = blockIdx.x;
    int b = bid >> 5, rg = bid & 31;
    int c0 = rg << 6;
    const float* xb = x + ((size_t)(b * A_ + c0)) * D_;
    int lane = t & 63, w = t >> 6, quad = lane >> 4, col = lane & 15;
    f32x4 accA = {0.f, 0.f, 0.f, 0.f}, accB = {0.f, 0.f, 0.f, 0.f};

    for (int dc = 0; dc < 8; ++dc) {
        int d0 = dc << 6;
        __syncthreads();                           // covers Wc on dc=0, xs reuse after
        // coop load 64c x 64d fp32, chunk-XOR swizzle
#pragma unroll
        for (int j = 0; j < 4; ++j) {
            int idx = t + 256 * j;
            int c = idx >> 4, ch = idx & 15;
            float4 v = *(const float4*)(xb + (size_t)c * D_ + d0 + ch * 4);
            *(float4*)&xs[c * 64 + ((ch ^ (c & 15)) << 2)] = v;
        }
        __syncthreads();
        // transpose write-out: xT[b][d0+d][c0 + cq..cq+3] as half4
        _Float16* xo = xT + ((size_t)b * D_ + d0) * A_ + c0;
#pragma unroll
        for (int j = 0; j < 4; ++j) {
            int idx = t + 256 * j;
            int d = idx >> 4, cq = (idx & 15) << 2;
            int ch = d >> 2, e = d & 3;
            half4 h;
#pragma unroll
            for (int k = 0; k < 4; ++k) {
                int c = cq + k;
                h[k] = (_Float16)xs[c * 64 + ((ch ^ (c & 15)) << 2) + e];
            }
            *(half4*)(xo + (size_t)d * A_ + cq) = h;
        }
        // factor MFMAs: wave w owns rows w*16..w*16+15 (A row = col)
#pragma unroll
        for (int kt = 0; kt < 2; ++kt) {
            int kk = kt * 32 + quad * 8;
            int r = w * 16 + col;
            int ch0 = kk >> 2;                      // even
            float4 v0 = *(const float4*)&xs[r * 64 + ((ch0 ^ col) << 2)];
            float4 v1 = *(const float4*)&xs[r * 64 + (((ch0 + 1) ^ col) << 2)];
            half8 af;
            af[0] = (_Float16)v0.x; af[1] = (_Float16)v0.y; af[2] = (_Float16)v0.z; af[3] = (_Float16)v0.w;
            af[4] = (_Float16)v1.x; af[5] = (_Float16)v1.y; af[6] = (_Float16)v1.z; af[7] = (_Float16)v1.w;
            int k = d0 + kk;
            half8 bf0 = *(const half8*)&Wc[col * 520 + k];
            half8 bf1 = *(const half8*)&Wc[(col + 16) * 520 + k];
            accA = __builtin_amdgcn_mfma_f32_16x16x32_f16(af, bf0, accA, 0, 0, 0);
            accB = __builtin_amdgcn_mfma_f32_16x16x32_f16(af, bf1, accB, 0, 0, 0);
        }
    }
#pragma unroll
    for (int q = 0; q < 4; ++q) {
        size_t grow = (size_t)bid * 64 + w * 16 + quad * 4 + q;
        if (col < 10) left[grow * 10 + col] = accA[q];
        if (col < 12) rightT[grow * 12 + col] = (_Float16)accB[q];  // cols 10,11 exact 0
    }
}

// ------------- K3: fused P recompute + softmax denom + (P@x) MFMA GEMM -------------
// Block: 128a x 256d tile, 4 waves (wave = 64a x 128d), K-loop c in steps of 32.
// Each block spans all c for its a-rows -> row sums accumulated in-kernel.
__global__ __launch_bounds__(256, 2) void k3_attn(const _Float16* __restrict__ xT,
                                                  const float* __restrict__ left,
                                                  const _Float16* __restrict__ rightT,
                                                  float* __restrict__ out) {
    __shared__ _Float16 XTl[256 * 32];   // [d-local][c-chunk], rows 64B, XOR-swizzled
    __shared__ _Float16 Ps[128 * 40];    // [a-local][c], stride 40 f16 (2-way banks)
    __shared__ _Float16 rl[32 * 40];     // [c-local][r padded to 32]
    __shared__ float rowsum[128];
    int t = threadIdx.x, lane = t & 63, w = t >> 6;
    int quad = lane >> 4, c16 = lane & 15;
    int bid = blockIdx.x;
    int nb = bid & 1, at = (bid >> 1) & 15, b = bid >> 5;
    int a0 = at << 7, n0 = nb << 8;
    int waveM = w & 1, waveN = w >> 1;

    // zero rl pad r in [12,32) for all 32 rows
    for (int i = t; i < 320; i += 256) {
        int c = i / 10, dw = i % 10;
        *(uint32_t*)((char*)rl + c * 80 + 24 + dw * 4) = 0u;
    }

    // left A-frags (static): wave w owns P row-tiles m = 2w, 2w+1
    half8 lf[2];
#pragma unroll
    for (int i = 0; i < 2; ++i) {
        int arow = a0 + (2 * w + i) * 16 + c16;
        const float* lp = left + (size_t)((b << 11) + arow) * 10;
#pragma unroll
        for (int j = 0; j < 8; ++j) {
            int r = quad * 8 + j;
            lf[i][j] = (r < 10) ? (_Float16)lp[r] : (_Float16)0.f;
        }
    }

    f32x4 acc[4][8];
#pragma unroll
    for (int mi = 0; mi < 4; ++mi)
#pragma unroll
        for (int ni = 0; ni < 8; ++ni) acc[mi][ni] = (f32x4){0.f, 0.f, 0.f, 0.f};
    float psum[2][4] = {{0.f, 0.f, 0.f, 0.f}, {0.f, 0.f, 0.f, 0.f}};

    const _Float16* xTb = xT + ((size_t)b * D_ + n0) * A_;
    const _Float16* rTb = rightT + (size_t)(b << 11) * 12;

    int psA[4];
#pragma unroll
    for (int mi = 0; mi < 4; ++mi) psA[mi] = (waveM * 64 + mi * 16 + c16) * 80 + quad * 16;
    int xtB[8];
#pragma unroll
    for (int ni = 0; ni < 8; ++ni) {
        int nr = waveN * 128 + ni * 16 + c16;
        xtB[ni] = nr * 64 + ((quad ^ ((nr >> 1) & 3)) << 4);
    }
    int rlB[2];
#pragma unroll
    for (int kh = 0; kh < 2; ++kh) rlB[kh] = (kh * 16 + c16) * 80 + quad * 16;

    int nloc0 = w * 64 + (lane >> 2);
    int kq = lane & 3;

    for (int kt = 0; kt < 64; ++kt) {
        int c0 = kt << 5;
        __syncthreads();
        if (t < 192) {                    // stage rightT tile: 32c x 6 dwords
            int c = t / 6, dw = t % 6;
            uint32_t v = *(const uint32_t*)((const char*)(rTb + (size_t)(c0 + c) * 12) + dw * 4);
            *(uint32_t*)((char*)rl + c * 80 + dw * 4) = v;
        }
#pragma unroll
        for (int cc = 0; cc < 4; ++cc) {  // DMA XT tile: 16 rows x 64B per call
            int nl = nloc0 + cc * 16;
            int kqs = kq ^ ((nl >> 1) & 3);
            const _Float16* src = xTb + (size_t)nl * A_ + c0 + kqs * 8;
            _Float16* dst = &XTl[(w * 64 + cc * 16) * 32];
            __builtin_amdgcn_global_load_lds((const __attribute__((address_space(1))) void*)src,
                                             (__attribute__((address_space(3))) void*)dst,
                                             16, 0, 0);
        }
        __syncthreads();
        // P phase: scores -> exp -> psum + Ps (A-operand layout)
#pragma unroll
        for (int kh = 0; kh < 2; ++kh) {
            half8 bfr = *(const half8*)((const char*)rl + rlB[kh]);
#pragma unroll
            for (int i = 0; i < 2; ++i) {
                f32x4 z = {0.f, 0.f, 0.f, 0.f};
                f32x4 pc = __builtin_amdgcn_mfma_f32_16x16x32_f16(lf[i], bfr, z, 0, 0, 0);
#pragma unroll
                for (int q = 0; q < 4; ++q) {
                    float p = __expf(pc[q]);
                    psum[i][q] += p;
                    Ps[((2 * w + i) * 16 + quad * 4 + q) * 40 + kh * 16 + c16] = (_Float16)p;
                }
            }
        }
        __syncthreads();
        // main GEMM phase
        half8 af[4], bf[8];
#pragma unroll
        for (int mi = 0; mi < 4; ++mi) af[mi] = *(const half8*)((const char*)Ps + psA[mi]);
#pragma unroll
        for (int ni = 0; ni < 8; ++ni) bf[ni] = *(const half8*)((const char*)XTl + xtB[ni]);
#pragma unroll
        for (int mi = 0; mi < 4; ++mi)
#pragma unroll
            for (int ni = 0; ni < 8; ++ni)
                acc[mi][ni] = __builtin_amdgcn_mfma_f32_16x16x32_f16(af[mi], bf[ni], acc[mi][ni], 0, 0, 0);
    }

    // row sums: reduce over the 16 column lanes (c16), write per-row
#pragma unroll
    for (int i = 0; i < 2; ++i)
#pragma unroll
        for (int q = 0; q < 4; ++q) {
            float s = psum[i][q];
            s += __shfl_xor(s, 1);
            s += __shfl_xor(s, 2);
            s += __shfl_xor(s, 4);
            s += __shfl_xor(s, 8);
            if (c16 == 0) rowsum[(2 * w + i) * 16 + quad * 4 + q] = s;
        }
    __syncthreads();

    float* ob = out + ((size_t)b * A_ + a0) * D_ + n0;
#pragma unroll
    for (int mi = 0; mi < 4; ++mi) {
#pragma unroll
        for (int q = 0; q < 4; ++q) {
            int ar = waveM * 64 + mi * 16 + quad * 4 + q;
            float sc = 1.0f / rowsum[ar];
#pragma unroll
            for (int ni = 0; ni < 8; ++ni)
                ob[(size_t)ar * D_ + waveN * 128 + ni * 16 + c16] = acc[mi][ni][q] * sc;
        }
    }
}

extern "C" void kernel_launch(void* const* d_in, const int* in_sizes, int n_in,
                              void* d_out, int out_size, void* d_ws, size_t ws_size,
                              hipStream_t stream) {
    const float* x  = (const float*)d_in[0];
    const float* W1 = (const float*)d_in[1];
    const float* W2 = (const float*)d_in[2];
    float* out = (float*)d_out;
    char* ws = (char*)d_ws;
    // ws layout (bytes): xT f16 [16][512][2048] @0 (33,554,432)
    //                    left fp32 [32768][10] @33,554,432 (1,310,720)
    //                    rightT f16 [32768][12] @34,865,152 (786,432)  total ~35.7 MB
    _Float16* xT    = (_Float16*)ws;
    float*    left  = (float*)(ws + 33554432);
    _Float16* rightT= (_Float16*)(ws + 34865152);

    k01_prep<<<512, 256, 0, stream>>>(x, W1, W2, xT, left, rightT);
    k3_attn<<<512, 256, 0, stream>>>(xT, left, rightT, out);
}